// Round 10
// baseline (315.983 us; speedup 1.0000x reference)
//
#include <hip/hip_runtime.h>
#include <float.h>

#define N_NODES 50000
#define N_EDGES 600000
#define D 128
#define N_GRAPHS 64
#define SCAN_T 256
#define SCAN_NBLK ((N_NODES + SCAN_T - 1) / SCAN_T)   // 196

typedef __attribute__((ext_vector_type(8))) short short8;   // 8 bf16 = 4 VGPRs
typedef __attribute__((ext_vector_type(4))) float floatx4;

__device__ inline float bf2f(unsigned short h) {
    return __uint_as_float((unsigned)h << 16);
}
__device__ inline unsigned short f2bf(float f) {
    unsigned u = __float_as_uint(f);
    return (unsigned short)((u + 0x7fffu + ((u >> 16) & 1u)) >> 16);   // RNE
}

// ------- fused prep + casts: zero deg, init g, x -> bf16, weights -> Bb --------
// Bb[o][k] row-major-in-k IS the MFMA B-fragment layout (n fixed, k contiguous).

__global__ void cast_prep(const float4* __restrict__ x, ushort4* __restrict__ xb, int n4,
                          const float* __restrict__ Wr0, const float* __restrict__ Wo0,
                          const float* __restrict__ Wr1, const float* __restrict__ Wo1,
                          const float* __restrict__ Wr2, const float* __restrict__ Wo2,
                          unsigned short* __restrict__ B0, unsigned short* __restrict__ B1,
                          unsigned short* __restrict__ B2,
                          int* __restrict__ deg, float* __restrict__ g) {
    int idx = blockIdx.x * 256 + threadIdx.x;
    if (idx < N_NODES) deg[idx] = 0;
    if (idx < N_GRAPHS * D) g[idx] = -FLT_MAX;
    if (idx < n4) {
        float4 v = x[idx];
        ushort4 o;
        o.x = f2bf(v.x); o.y = f2bf(v.y); o.z = f2bf(v.z); o.w = f2bf(v.w);
        xb[idx] = o;
        return;
    }
    int w = idx - n4;                        // 0 .. 3*32768-1
    if (w >= 3 * 128 * 256) return;
    int l = w >> 15;
    int r = w & 32767;
    int o = r >> 8, k = r & 255;
    const float* Wr = (l == 0) ? Wr0 : (l == 1) ? Wr1 : Wr2;
    const float* Wo = (l == 0) ? Wo0 : (l == 1) ? Wo1 : Wo2;
    unsigned short* B = (l == 0) ? B0 : (l == 1) ? B1 : B2;
    float v = (k < 128) ? Wr[o * 128 + k] : Wo[o * 128 + (k - 128)];
    B[r] = f2bf(v);
}

// ---------------- CSR build (once per launch) ----------------------------------

__global__ void count_deg(const int* __restrict__ ei, int* __restrict__ deg) {
    int e = blockIdx.x * 256 + threadIdx.x;
    if (e < N_EDGES) atomicAdd(&deg[ei[N_EDGES + e]], 1);
}

__global__ __launch_bounds__(SCAN_T) void block_sum(const int* __restrict__ deg,
                                                    int* __restrict__ blockSums) {
    __shared__ int s[SCAN_T];
    int tid = threadIdx.x;
    int i = blockIdx.x * SCAN_T + tid;
    s[tid] = (i < N_NODES) ? deg[i] : 0;
    __syncthreads();
    for (int off = SCAN_T / 2; off > 0; off >>= 1) {
        if (tid < off) s[tid] += s[tid + off];
        __syncthreads();
    }
    if (tid == 0) blockSums[blockIdx.x] = s[0];
}

__global__ __launch_bounds__(SCAN_T) void scan_blocks(const int* __restrict__ blockSums,
                                                      int* __restrict__ blockOff,
                                                      int* __restrict__ row_start) {
    __shared__ int s[SCAN_T];
    int tid = threadIdx.x;
    int v = (tid < SCAN_NBLK) ? blockSums[tid] : 0;
    s[tid] = v;
    __syncthreads();
    for (int off = 1; off < SCAN_T; off <<= 1) {
        int t = (tid >= off) ? s[tid - off] : 0;
        __syncthreads();
        s[tid] += t;
        __syncthreads();
    }
    if (tid < SCAN_NBLK) blockOff[tid] = s[tid] - v;
    if (tid == SCAN_T - 1) row_start[N_NODES] = s[tid];
}

__global__ __launch_bounds__(SCAN_T) void scan_write(const int* __restrict__ deg,
                                                     const int* __restrict__ blockOff,
                                                     int* __restrict__ row_start,
                                                     int* __restrict__ cursor) {
    __shared__ int s[SCAN_T];
    int tid = threadIdx.x;
    int i = blockIdx.x * SCAN_T + tid;
    int v = (i < N_NODES) ? deg[i] : 0;
    s[tid] = v;
    __syncthreads();
    for (int off = 1; off < SCAN_T; off <<= 1) {
        int t = (tid >= off) ? s[tid - off] : 0;
        __syncthreads();
        s[tid] += t;
        __syncthreads();
    }
    if (i < N_NODES) {
        int rs = blockOff[blockIdx.x] + s[tid] - v;
        row_start[i] = rs;
        cursor[i]    = rs;
    }
}

__global__ void fill_csr(const int* __restrict__ ei, int* __restrict__ cursor,
                         int* __restrict__ csr_src) {
    int e = blockIdx.x * 256 + threadIdx.x;
    if (e < N_EDGES) {
        int dst = ei[N_EDGES + e];
        int pos = atomicAdd(&cursor[dst], 1);
        csr_src[pos] = ei[e];
    }
}

// ---------------- aggregation: paired-edge 16B gather --------------------------
// 32-lane group per node. Lanes 0-15 cover the full 256B row of edge j (16 x
// ushort8), lanes 16-31 cover edge j+1; 4-edge unroll = 2 independent 16B
// loads in flight per lane. One shfl_xor(16) stage merges the halves.
// Halves vmem+shfl instructions per edge and the serial trip count vs R9.

__global__ __launch_bounds__(256) void csr_gather_bf16(
    const unsigned short* __restrict__ xb, const int* __restrict__ row_start,
    const int* __restrict__ csr_src, unsigned short* __restrict__ aggb)
{
    int node = blockIdx.x * 8 + (threadIdx.x >> 5);
    int lane = threadIdx.x & 31;
    int half = lane >> 4;        // which edge of the pair
    int fl   = lane & 15;        // feature octant: features fl*8 .. fl*8+7
    if (node >= N_NODES) return;
    int beg = row_start[node];
    int end = row_start[node + 1];

    float a[8];
#pragma unroll
    for (int k = 0; k < 8; ++k) a[k] = 0.f;

    const unsigned short* xfb = xb + fl * 8;
    for (int base = beg; base < end; base += 32) {
        int n = end - base; if (n > 32) n = 32;
        int idx = (lane < n) ? csr_src[base + lane] : 0;   // one coalesced load
        int j = 0;
        for (; j + 3 < n; j += 4) {
            int s0 = __shfl(idx, j + half,     32);
            int s1 = __shfl(idx, j + 2 + half, 32);
            short8 u0 = *(const short8*)(xfb + (size_t)s0 * D);
            short8 u1 = *(const short8*)(xfb + (size_t)s1 * D);
#pragma unroll
            for (int k = 0; k < 8; ++k)
                a[k] += bf2f((unsigned short)u0[k]) + bf2f((unsigned short)u1[k]);
        }
        for (; j + 1 < n; j += 2) {
            int s0 = __shfl(idx, j + half, 32);
            short8 u0 = *(const short8*)(xfb + (size_t)s0 * D);
#pragma unroll
            for (int k = 0; k < 8; ++k) a[k] += bf2f((unsigned short)u0[k]);
        }
        if (j < n) {                         // odd tail: lower half only
            int s0 = __shfl(idx, j, 32);
            if (half == 0) {
                short8 u0 = *(const short8*)(xfb + (size_t)s0 * D);
#pragma unroll
                for (int k = 0; k < 8; ++k) a[k] += bf2f((unsigned short)u0[k]);
            }
        }
    }

#pragma unroll
    for (int k = 0; k < 8; ++k) a[k] += __shfl_xor(a[k], 16, 32);
    if (half == 0) {
        short8 r;
#pragma unroll
        for (int k = 0; k < 8; ++k) r[k] = (short)f2bf(a[k]);
        *(short8*)(aggb + (size_t)node * D + fl * 8) = r;
    }
}

// ---------------- B staging: global -> LDS, MFMA-fragment order ----------------
// sB[(ksL*8+t)*64 + lane]: consecutive lanes -> consecutive 16B -> conflict-free.

__device__ inline void stage_b_half(unsigned short* sB, const unsigned short* __restrict__ Bb,
                                    int tid, int h) {
#pragma unroll
    for (int i = 0; i < 8; ++i) {
        int flat = tid + i * 256;            // 0..2047
        int fi = flat >> 6, ln = flat & 63;  // frag idx / lane
        int mm = ln & 15, qq = ln >> 4;
        int ksL = fi >> 3, tt = fi & 7;
        short8 v = *(const short8*)(Bb + (size_t)(tt * 16 + mm) * 256
                                    + (h * 4 + ksL) * 32 + qq * 8);
        *(short8*)(sB + (size_t)flat * 8) = v;
    }
}

// ---------------- MFMA GEMM: O = [aggb|xb] @ Bb^T + bias (+relu) --------------

__global__ __launch_bounds__(256) void gemm_mfma(
    const unsigned short* __restrict__ aggb, const unsigned short* __restrict__ xb,
    const unsigned short* __restrict__ Bb, const float* __restrict__ bias,
    unsigned short* __restrict__ Ob, int relu)
{
    __shared__ unsigned short sB[16384];     // 32 KB
    int tid  = threadIdx.x;
    int wave = tid >> 6;
    int lane = tid & 63;
    int m    = lane & 15;
    int quad = lane >> 4;
    int row0 = blockIdx.x * 64 + wave * 16;

    int arow = row0 + m;
    if (arow > N_NODES - 1) arow = N_NODES - 1;

    short8 af[8];
#pragma unroll
    for (int ks = 0; ks < 8; ++ks) {
        const unsigned short* Asrc = (ks < 4) ? aggb : xb;
        af[ks] = *(const short8*)(Asrc + (size_t)arow * 128 + (ks & 3) * 32 + quad * 8);
    }

    floatx4 acc[8];
#pragma unroll
    for (int t = 0; t < 8; ++t) acc[t] = (floatx4){0.f, 0.f, 0.f, 0.f};

    stage_b_half(sB, Bb, tid, 0);
    __syncthreads();
#pragma unroll
    for (int ksL = 0; ksL < 4; ++ksL)
#pragma unroll
        for (int t = 0; t < 8; ++t) {
            short8 b = *(const short8*)(sB + (size_t)((ksL * 8 + t) * 64 + lane) * 8);
            acc[t] = __builtin_amdgcn_mfma_f32_16x16x32_bf16(af[ksL], b, acc[t], 0, 0, 0);
        }
    __syncthreads();
    stage_b_half(sB, Bb, tid, 1);
    __syncthreads();
#pragma unroll
    for (int ksL = 0; ksL < 4; ++ksL)
#pragma unroll
        for (int t = 0; t < 8; ++t) {
            short8 b = *(const short8*)(sB + (size_t)((ksL * 8 + t) * 64 + lane) * 8);
            acc[t] = __builtin_amdgcn_mfma_f32_16x16x32_bf16(af[4 + ksL], b, acc[t], 0, 0, 0);
        }

#pragma unroll
    for (int t = 0; t < 8; ++t) {
        int col = t * 16 + m;                     // C/D: col=lane&15
        float bv = bias[col];
#pragma unroll
        for (int r = 0; r < 4; ++r) {
            int row = row0 + quad * 4 + r;        // C/D: row=quad*4+reg
            if (row >= N_NODES) continue;
            float v = acc[t][r] + bv;
            if (relu) v = fmaxf(v, 0.f);
            Ob[(size_t)row * D + col] = f2bf(v);
        }
    }
}

// ---------------- layer-3 GEMM with fused pooled max ---------------------------

struct PoolShared {
    union {
        unsigned short b[16384];     // 32 KB B-half
        float c[64 * 129];           // 33 KB C tile
    };
};

__global__ __launch_bounds__(256) void gemm_pool(
    const unsigned short* __restrict__ aggb, const unsigned short* __restrict__ xb,
    const unsigned short* __restrict__ Bb, const float* __restrict__ bias,
    const int* __restrict__ batch, float* __restrict__ g)
{
    __shared__ PoolShared sh;
    __shared__ int bl[64];
    int tid  = threadIdx.x;
    int wave = tid >> 6;
    int lane = tid & 63;
    int m    = lane & 15;
    int quad = lane >> 4;
    int row0 = blockIdx.x * 64;

    int arow = row0 + wave * 16 + m;
    if (arow > N_NODES - 1) arow = N_NODES - 1;

    short8 af[8];
#pragma unroll
    for (int ks = 0; ks < 8; ++ks) {
        const unsigned short* Asrc = (ks < 4) ? aggb : xb;
        af[ks] = *(const short8*)(Asrc + (size_t)arow * 128 + (ks & 3) * 32 + quad * 8);
    }

    floatx4 acc[8];
#pragma unroll
    for (int t = 0; t < 8; ++t) acc[t] = (floatx4){0.f, 0.f, 0.f, 0.f};

    stage_b_half(sh.b, Bb, tid, 0);
    __syncthreads();
#pragma unroll
    for (int ksL = 0; ksL < 4; ++ksL)
#pragma unroll
        for (int t = 0; t < 8; ++t) {
            short8 b = *(const short8*)(sh.b + (size_t)((ksL * 8 + t) * 64 + lane) * 8);
            acc[t] = __builtin_amdgcn_mfma_f32_16x16x32_bf16(af[ksL], b, acc[t], 0, 0, 0);
        }
    __syncthreads();
    stage_b_half(sh.b, Bb, tid, 1);
    __syncthreads();
#pragma unroll
    for (int ksL = 0; ksL < 4; ++ksL)
#pragma unroll
        for (int t = 0; t < 8; ++t) {
            short8 b = *(const short8*)(sh.b + (size_t)((ksL * 8 + t) * 64 + lane) * 8);
            acc[t] = __builtin_amdgcn_mfma_f32_16x16x32_bf16(af[4 + ksL], b, acc[t], 0, 0, 0);
        }
    __syncthreads();                         // all sB reads done; reuse as C tile

#pragma unroll
    for (int t = 0; t < 8; ++t) {
        int col = t * 16 + m;
        float bv = bias[col];
#pragma unroll
        for (int r = 0; r < 4; ++r)
            sh.c[(wave * 16 + quad * 4 + r) * 129 + col] = acc[t][r] + bv;
    }
    if (tid < 64) {
        int grow = row0 + tid;
        bl[tid] = (grow < N_NODES) ? batch[grow] : -1;
    }
    __syncthreads();

    int nvalid = min(64, N_NODES - row0);
    int b0 = bl[0], b1 = bl[nvalid - 1];     // batch sorted; 1-3 graphs per block
    int col  = tid & 127;
    int rbeg = (tid >> 7) * 32;
    for (int gg = b0; gg <= b1; ++gg) {
        float cur = -FLT_MAX;
#pragma unroll
        for (int r = 0; r < 32; ++r) {
            int rr = rbeg + r;
            float v = (bl[rr] == gg) ? sh.c[rr * 129 + col] : -FLT_MAX;
            cur = fmaxf(cur, v);
        }
        if (cur > -FLT_MAX) {
            float* ad = &g[gg * D + col];
            if (cur >= 0.f) atomicMax((int*)ad, __float_as_int(cur));
            else            atomicMin((unsigned int*)ad, __float_as_uint(cur));
        }
    }
}

// ---------------- head ---------------------------------------------------------

__global__ void mlp_head(const float* __restrict__ g,
                         const float* __restrict__ W1, const float* __restrict__ b1,
                         const float* __restrict__ W2, const float* __restrict__ b2,
                         float* __restrict__ out) {
    int gi = threadIdx.x;
    if (gi >= N_GRAPHS) return;
    float h[5];
#pragma unroll
    for (int j = 0; j < 5; ++j) {
        float acc = b1[j];
        for (int k = 0; k < D; ++k) acc += g[gi * D + k] * W1[j * D + k];
        h[j] = fmaxf(acc, 0.f);
    }
    float o = b2[0];
#pragma unroll
    for (int j = 0; j < 5; ++j) o += h[j] * W2[j];
    out[gi] = o;
}

extern "C" void kernel_launch(void* const* d_in, const int* in_sizes, int n_in,
                              void* d_out, int out_size, void* d_ws, size_t ws_size,
                              hipStream_t stream) {
    const float* x     = (const float*)d_in[0];
    const int*   ei    = (const int*)d_in[1];
    const int*   batch = (const int*)d_in[2];
    const float* Wrel[3]  = {(const float*)d_in[3], (const float*)d_in[6], (const float*)d_in[9]};
    const float* brel[3]  = {(const float*)d_in[4], (const float*)d_in[7], (const float*)d_in[10]};
    const float* Wroot[3] = {(const float*)d_in[5], (const float*)d_in[8], (const float*)d_in[11]};
    const float* W1 = (const float*)d_in[12];
    const float* b1 = (const float*)d_in[13];
    const float* W2 = (const float*)d_in[14];
    const float* b2 = (const float*)d_in[15];
    float* out = (float*)d_out;

    char* ws = (char*)d_ws;
    const size_t nodeB16 = (size_t)N_NODES * D * sizeof(unsigned short);   // 12.8 MB
    unsigned short* xb   = (unsigned short*)(ws);
    unsigned short* aggb = (unsigned short*)(ws + nodeB16);
    unsigned short* hb1  = (unsigned short*)(ws + 2 * nodeB16);
    unsigned short* hb2  = (unsigned short*)(ws + 3 * nodeB16);
    char* p = ws + 4 * nodeB16;
    unsigned short* Bb0 = (unsigned short*)p;   p += 128 * 256 * sizeof(unsigned short);
    unsigned short* Bb1 = (unsigned short*)p;   p += 128 * 256 * sizeof(unsigned short);
    unsigned short* Bb2 = (unsigned short*)p;   p += 128 * 256 * sizeof(unsigned short);
    float* g        = (float*)p;                p += N_GRAPHS * D * sizeof(float);
    int*   deg      = (int*)p;                  p += N_NODES * sizeof(int);
    int*   row_start= (int*)p;                  p += (N_NODES + 1) * sizeof(int);
    int*   cursor   = (int*)p;                  p += N_NODES * sizeof(int);
    int*   csr_src  = (int*)p;                  p += N_EDGES * sizeof(int);
    int*   blockSums= (int*)p;                  p += SCAN_NBLK * sizeof(int);
    int*   blockOff = (int*)p;                  p += SCAN_NBLK * sizeof(int);

    // fused prep + bf16 conversions (runs first; zeroes deg for count_deg)
    const int n4 = N_NODES * D / 4;                       // 1.6M
    const int cast_total = n4 + 3 * 128 * 256;
    cast_prep<<<(cast_total + 255) / 256, 256, 0, stream>>>(
        (const float4*)x, (ushort4*)xb, n4,
        Wrel[0], Wroot[0], Wrel[1], Wroot[1], Wrel[2], Wroot[2],
        Bb0, Bb1, Bb2, deg, g);

    // CSR build (once per call)
    count_deg<<<(N_EDGES + 255) / 256, 256, 0, stream>>>(ei, deg);
    block_sum<<<SCAN_NBLK, SCAN_T, 0, stream>>>(deg, blockSums);
    scan_blocks<<<1, SCAN_T, 0, stream>>>(blockSums, blockOff, row_start);
    scan_write<<<SCAN_NBLK, SCAN_T, 0, stream>>>(deg, blockOff, row_start, cursor);
    fill_csr<<<(N_EDGES + 255) / 256, 256, 0, stream>>>(ei, cursor, csr_src);

    const int ggrid = (N_NODES + 7) / 8;                  // 6250
    const int mgrid = (N_NODES + 63) / 64;                // 782

    csr_gather_bf16<<<ggrid, 256, 0, stream>>>(xb, row_start, csr_src, aggb);
    gemm_mfma<<<mgrid, 256, 0, stream>>>(aggb, xb, Bb0, brel[0], hb1, 1);

    csr_gather_bf16<<<ggrid, 256, 0, stream>>>(hb1, row_start, csr_src, aggb);
    gemm_mfma<<<mgrid, 256, 0, stream>>>(aggb, hb1, Bb1, brel[1], hb2, 1);

    csr_gather_bf16<<<ggrid, 256, 0, stream>>>(hb2, row_start, csr_src, aggb);
    gemm_pool<<<mgrid, 256, 0, stream>>>(aggb, hb2, Bb2, brel[2], batch, g);

    mlp_head<<<1, 64, 0, stream>>>(g, W1, b1, W2, b2, out);
}

// Round 11
// 304.828 us; speedup vs baseline: 1.0366x; 1.0366x over previous
//
#include <hip/hip_runtime.h>
#include <float.h>

#define N_NODES 50000
#define N_EDGES 600000
#define D 128
#define N_GRAPHS 64
#define SCAN_T 256
#define SCAN_NBLK ((N_NODES + SCAN_T - 1) / SCAN_T)   // 196

typedef __attribute__((ext_vector_type(8))) short short8;   // 8 bf16 = 4 VGPRs
typedef __attribute__((ext_vector_type(4))) float floatx4;

__device__ inline float bf2f(unsigned short h) {
    return __uint_as_float((unsigned)h << 16);
}
__device__ inline unsigned short f2bf(float f) {
    unsigned u = __float_as_uint(f);
    return (unsigned short)((u + 0x7fffu + ((u >> 16) & 1u)) >> 16);   // RNE
}

// ------- fused prep + casts: zero deg, init g, x -> bf16, weights -> Bb --------
// Bb[o][k] row-major-in-k IS the MFMA B-fragment layout (n fixed, k contiguous).

__global__ void cast_prep(const float4* __restrict__ x, ushort4* __restrict__ xb, int n4,
                          const float* __restrict__ Wr0, const float* __restrict__ Wo0,
                          const float* __restrict__ Wr1, const float* __restrict__ Wo1,
                          const float* __restrict__ Wr2, const float* __restrict__ Wo2,
                          unsigned short* __restrict__ B0, unsigned short* __restrict__ B1,
                          unsigned short* __restrict__ B2,
                          int* __restrict__ deg, float* __restrict__ g) {
    int idx = blockIdx.x * 256 + threadIdx.x;
    if (idx < N_NODES) deg[idx] = 0;
    if (idx < N_GRAPHS * D) g[idx] = -FLT_MAX;
    if (idx < n4) {
        float4 v = x[idx];
        ushort4 o;
        o.x = f2bf(v.x); o.y = f2bf(v.y); o.z = f2bf(v.z); o.w = f2bf(v.w);
        xb[idx] = o;
        return;
    }
    int w = idx - n4;                        // 0 .. 3*32768-1
    if (w >= 3 * 128 * 256) return;
    int l = w >> 15;
    int r = w & 32767;
    int o = r >> 8, k = r & 255;
    const float* Wr = (l == 0) ? Wr0 : (l == 1) ? Wr1 : Wr2;
    const float* Wo = (l == 0) ? Wo0 : (l == 1) ? Wo1 : Wo2;
    unsigned short* B = (l == 0) ? B0 : (l == 1) ? B1 : B2;
    float v = (k < 128) ? Wr[o * 128 + k] : Wo[o * 128 + (k - 128)];
    B[r] = f2bf(v);
}

// ---------------- CSR build (once per launch) ----------------------------------

__global__ void count_deg(const int* __restrict__ ei, int* __restrict__ deg) {
    int e = blockIdx.x * 256 + threadIdx.x;
    if (e < N_EDGES) atomicAdd(&deg[ei[N_EDGES + e]], 1);
}

__global__ __launch_bounds__(SCAN_T) void block_sum(const int* __restrict__ deg,
                                                    int* __restrict__ blockSums) {
    __shared__ int s[SCAN_T];
    int tid = threadIdx.x;
    int i = blockIdx.x * SCAN_T + tid;
    s[tid] = (i < N_NODES) ? deg[i] : 0;
    __syncthreads();
    for (int off = SCAN_T / 2; off > 0; off >>= 1) {
        if (tid < off) s[tid] += s[tid + off];
        __syncthreads();
    }
    if (tid == 0) blockSums[blockIdx.x] = s[0];
}

// merged scan: every block redundantly scans the 196 block sums in LDS (cheap),
// takes its own exclusive offset, then does its local exclusive scan + write.
// Replaces the scan_blocks -> scan_write serial pair with one launch.
__global__ __launch_bounds__(SCAN_T) void scan_write(const int* __restrict__ deg,
                                                     const int* __restrict__ blockSums,
                                                     int* __restrict__ row_start,
                                                     int* __restrict__ cursor) {
    __shared__ int bs[SCAN_T];
    __shared__ int s[SCAN_T];
    int tid = threadIdx.x;
    bs[tid] = (tid < SCAN_NBLK) ? blockSums[tid] : 0;
    __syncthreads();
    for (int off = 1; off < SCAN_T; off <<= 1) {
        int t = (tid >= off) ? bs[tid - off] : 0;
        __syncthreads();
        bs[tid] += t;
        __syncthreads();
    }
    int myOff = (blockIdx.x == 0) ? 0 : bs[blockIdx.x - 1];
    if (blockIdx.x == 0 && tid == SCAN_T - 1) row_start[N_NODES] = bs[tid];

    int i = blockIdx.x * SCAN_T + tid;
    int v = (i < N_NODES) ? deg[i] : 0;
    s[tid] = v;
    __syncthreads();
    for (int off = 1; off < SCAN_T; off <<= 1) {
        int t = (tid >= off) ? s[tid - off] : 0;
        __syncthreads();
        s[tid] += t;
        __syncthreads();
    }
    if (i < N_NODES) {
        int rs = myOff + s[tid] - v;
        row_start[i] = rs;
        cursor[i]    = rs;
    }
}

__global__ void fill_csr(const int* __restrict__ ei, int* __restrict__ cursor,
                         int* __restrict__ csr_src) {
    int e = blockIdx.x * 256 + threadIdx.x;
    if (e < N_EDGES) {
        int dst = ei[N_EDGES + e];
        int pos = atomicAdd(&cursor[dst], 1);
        csr_src[pos] = ei[e];
    }
}

// ---------------- aggregation: shfl-broadcast gather, 8-way MLP ---------------
// (R9 form — best measured schedule: 32 lanes/node, coalesced index load,
// shfl broadcast, 8 independent ushort4 row-loads in flight per lane.)

__global__ __launch_bounds__(256) void csr_gather_bf16(
    const unsigned short* __restrict__ xb, const int* __restrict__ row_start,
    const int* __restrict__ csr_src, unsigned short* __restrict__ aggb)
{
    int node = blockIdx.x * 8 + (threadIdx.x >> 5);
    int lane = threadIdx.x & 31;
    if (node >= N_NODES) return;
    int beg = row_start[node];
    int end = row_start[node + 1];

    float a0 = 0.f, a1 = 0.f, a2 = 0.f, a3 = 0.f;   // feature lane*4 .. +3
    for (int base = beg; base < end; base += 32) {
        int n = end - base; if (n > 32) n = 32;
        int idx = (lane < n) ? csr_src[base + lane] : 0;   // one coalesced load
        int j = 0;
        for (; j + 7 < n; j += 8) {
            int s0 = __shfl(idx, j,     32); int s1 = __shfl(idx, j + 1, 32);
            int s2 = __shfl(idx, j + 2, 32); int s3 = __shfl(idx, j + 3, 32);
            int s4 = __shfl(idx, j + 4, 32); int s5 = __shfl(idx, j + 5, 32);
            int s6 = __shfl(idx, j + 6, 32); int s7 = __shfl(idx, j + 7, 32);
            ushort4 u0 = *(const ushort4*)(xb + (size_t)s0 * D + lane * 4);
            ushort4 u1 = *(const ushort4*)(xb + (size_t)s1 * D + lane * 4);
            ushort4 u2 = *(const ushort4*)(xb + (size_t)s2 * D + lane * 4);
            ushort4 u3 = *(const ushort4*)(xb + (size_t)s3 * D + lane * 4);
            ushort4 u4 = *(const ushort4*)(xb + (size_t)s4 * D + lane * 4);
            ushort4 u5 = *(const ushort4*)(xb + (size_t)s5 * D + lane * 4);
            ushort4 u6 = *(const ushort4*)(xb + (size_t)s6 * D + lane * 4);
            ushort4 u7 = *(const ushort4*)(xb + (size_t)s7 * D + lane * 4);
            a0 += bf2f(u0.x) + bf2f(u1.x) + bf2f(u2.x) + bf2f(u3.x)
                + bf2f(u4.x) + bf2f(u5.x) + bf2f(u6.x) + bf2f(u7.x);
            a1 += bf2f(u0.y) + bf2f(u1.y) + bf2f(u2.y) + bf2f(u3.y)
                + bf2f(u4.y) + bf2f(u5.y) + bf2f(u6.y) + bf2f(u7.y);
            a2 += bf2f(u0.z) + bf2f(u1.z) + bf2f(u2.z) + bf2f(u3.z)
                + bf2f(u4.z) + bf2f(u5.z) + bf2f(u6.z) + bf2f(u7.z);
            a3 += bf2f(u0.w) + bf2f(u1.w) + bf2f(u2.w) + bf2f(u3.w)
                + bf2f(u4.w) + bf2f(u5.w) + bf2f(u6.w) + bf2f(u7.w);
        }
        for (; j + 3 < n; j += 4) {
            int s0 = __shfl(idx, j,     32); int s1 = __shfl(idx, j + 1, 32);
            int s2 = __shfl(idx, j + 2, 32); int s3 = __shfl(idx, j + 3, 32);
            ushort4 u0 = *(const ushort4*)(xb + (size_t)s0 * D + lane * 4);
            ushort4 u1 = *(const ushort4*)(xb + (size_t)s1 * D + lane * 4);
            ushort4 u2 = *(const ushort4*)(xb + (size_t)s2 * D + lane * 4);
            ushort4 u3 = *(const ushort4*)(xb + (size_t)s3 * D + lane * 4);
            a0 += bf2f(u0.x) + bf2f(u1.x) + bf2f(u2.x) + bf2f(u3.x);
            a1 += bf2f(u0.y) + bf2f(u1.y) + bf2f(u2.y) + bf2f(u3.y);
            a2 += bf2f(u0.z) + bf2f(u1.z) + bf2f(u2.z) + bf2f(u3.z);
            a3 += bf2f(u0.w) + bf2f(u1.w) + bf2f(u2.w) + bf2f(u3.w);
        }
        for (; j < n; ++j) {
            int s0 = __shfl(idx, j, 32);
            ushort4 u0 = *(const ushort4*)(xb + (size_t)s0 * D + lane * 4);
            a0 += bf2f(u0.x); a1 += bf2f(u0.y); a2 += bf2f(u0.z); a3 += bf2f(u0.w);
        }
    }
    ushort4 r;
    r.x = f2bf(a0); r.y = f2bf(a1); r.z = f2bf(a2); r.w = f2bf(a3);
    *(ushort4*)(aggb + (size_t)node * D + lane * 4) = r;
}

// ---------------- B staging: global -> LDS, MFMA-fragment order ----------------
// sB[(ksL*8+t)*64 + lane]: consecutive lanes -> consecutive 16B -> conflict-free.

__device__ inline void stage_b_half(unsigned short* sB, const unsigned short* __restrict__ Bb,
                                    int tid, int h) {
#pragma unroll
    for (int i = 0; i < 8; ++i) {
        int flat = tid + i * 256;            // 0..2047
        int fi = flat >> 6, ln = flat & 63;  // frag idx / lane
        int mm = ln & 15, qq = ln >> 4;
        int ksL = fi >> 3, tt = fi & 7;
        short8 v = *(const short8*)(Bb + (size_t)(tt * 16 + mm) * 256
                                    + (h * 4 + ksL) * 32 + qq * 8);
        *(short8*)(sB + (size_t)flat * 8) = v;
    }
}

// ---------------- MFMA GEMM: O = [aggb|xb] @ Bb^T + bias (+relu) --------------

__global__ __launch_bounds__(256) void gemm_mfma(
    const unsigned short* __restrict__ aggb, const unsigned short* __restrict__ xb,
    const unsigned short* __restrict__ Bb, const float* __restrict__ bias,
    unsigned short* __restrict__ Ob, int relu)
{
    __shared__ unsigned short sB[16384];     // 32 KB
    int tid  = threadIdx.x;
    int wave = tid >> 6;
    int lane = tid & 63;
    int m    = lane & 15;
    int quad = lane >> 4;
    int row0 = blockIdx.x * 64 + wave * 16;

    int arow = row0 + m;
    if (arow > N_NODES - 1) arow = N_NODES - 1;

    short8 af[8];
#pragma unroll
    for (int ks = 0; ks < 8; ++ks) {
        const unsigned short* Asrc = (ks < 4) ? aggb : xb;
        af[ks] = *(const short8*)(Asrc + (size_t)arow * 128 + (ks & 3) * 32 + quad * 8);
    }

    floatx4 acc[8];
#pragma unroll
    for (int t = 0; t < 8; ++t) acc[t] = (floatx4){0.f, 0.f, 0.f, 0.f};

    stage_b_half(sB, Bb, tid, 0);
    __syncthreads();
#pragma unroll
    for (int ksL = 0; ksL < 4; ++ksL)
#pragma unroll
        for (int t = 0; t < 8; ++t) {
            short8 b = *(const short8*)(sB + (size_t)((ksL * 8 + t) * 64 + lane) * 8);
            acc[t] = __builtin_amdgcn_mfma_f32_16x16x32_bf16(af[ksL], b, acc[t], 0, 0, 0);
        }
    __syncthreads();
    stage_b_half(sB, Bb, tid, 1);
    __syncthreads();
#pragma unroll
    for (int ksL = 0; ksL < 4; ++ksL)
#pragma unroll
        for (int t = 0; t < 8; ++t) {
            short8 b = *(const short8*)(sB + (size_t)((ksL * 8 + t) * 64 + lane) * 8);
            acc[t] = __builtin_amdgcn_mfma_f32_16x16x32_bf16(af[4 + ksL], b, acc[t], 0, 0, 0);
        }

#pragma unroll
    for (int t = 0; t < 8; ++t) {
        int col = t * 16 + m;                     // C/D: col=lane&15
        float bv = bias[col];
#pragma unroll
        for (int r = 0; r < 4; ++r) {
            int row = row0 + quad * 4 + r;        // C/D: row=quad*4+reg
            if (row >= N_NODES) continue;
            float v = acc[t][r] + bv;
            if (relu) v = fmaxf(v, 0.f);
            Ob[(size_t)row * D + col] = f2bf(v);
        }
    }
}

// ---------------- layer-3 GEMM with fused pooled max ---------------------------

struct PoolShared {
    union {
        unsigned short b[16384];     // 32 KB B-half
        float c[64 * 129];           // 33 KB C tile
    };
};

__global__ __launch_bounds__(256) void gemm_pool(
    const unsigned short* __restrict__ aggb, const unsigned short* __restrict__ xb,
    const unsigned short* __restrict__ Bb, const float* __restrict__ bias,
    const int* __restrict__ batch, float* __restrict__ g)
{
    __shared__ PoolShared sh;
    __shared__ int bl[64];
    int tid  = threadIdx.x;
    int wave = tid >> 6;
    int lane = tid & 63;
    int m    = lane & 15;
    int quad = lane >> 4;
    int row0 = blockIdx.x * 64;

    int arow = row0 + wave * 16 + m;
    if (arow > N_NODES - 1) arow = N_NODES - 1;

    short8 af[8];
#pragma unroll
    for (int ks = 0; ks < 8; ++ks) {
        const unsigned short* Asrc = (ks < 4) ? aggb : xb;
        af[ks] = *(const short8*)(Asrc + (size_t)arow * 128 + (ks & 3) * 32 + quad * 8);
    }

    floatx4 acc[8];
#pragma unroll
    for (int t = 0; t < 8; ++t) acc[t] = (floatx4){0.f, 0.f, 0.f, 0.f};

    stage_b_half(sh.b, Bb, tid, 0);
    __syncthreads();
#pragma unroll
    for (int ksL = 0; ksL < 4; ++ksL)
#pragma unroll
        for (int t = 0; t < 8; ++t) {
            short8 b = *(const short8*)(sh.b + (size_t)((ksL * 8 + t) * 64 + lane) * 8);
            acc[t] = __builtin_amdgcn_mfma_f32_16x16x32_bf16(af[ksL], b, acc[t], 0, 0, 0);
        }
    __syncthreads();
    stage_b_half(sh.b, Bb, tid, 1);
    __syncthreads();
#pragma unroll
    for (int ksL = 0; ksL < 4; ++ksL)
#pragma unroll
        for (int t = 0; t < 8; ++t) {
            short8 b = *(const short8*)(sh.b + (size_t)((ksL * 8 + t) * 64 + lane) * 8);
            acc[t] = __builtin_amdgcn_mfma_f32_16x16x32_bf16(af[4 + ksL], b, acc[t], 0, 0, 0);
        }
    __syncthreads();                         // all sB reads done; reuse as C tile

#pragma unroll
    for (int t = 0; t < 8; ++t) {
        int col = t * 16 + m;
        float bv = bias[col];
#pragma unroll
        for (int r = 0; r < 4; ++r)
            sh.c[(wave * 16 + quad * 4 + r) * 129 + col] = acc[t][r] + bv;
    }
    if (tid < 64) {
        int grow = row0 + tid;
        bl[tid] = (grow < N_NODES) ? batch[grow] : -1;
    }
    __syncthreads();

    int nvalid = min(64, N_NODES - row0);
    int b0 = bl[0], b1 = bl[nvalid - 1];     // batch sorted; 1-3 graphs per block
    int col  = tid & 127;
    int rbeg = (tid >> 7) * 32;
    for (int gg = b0; gg <= b1; ++gg) {
        float cur = -FLT_MAX;
#pragma unroll
        for (int r = 0; r < 32; ++r) {
            int rr = rbeg + r;
            float v = (bl[rr] == gg) ? sh.c[rr * 129 + col] : -FLT_MAX;
            cur = fmaxf(cur, v);
        }
        if (cur > -FLT_MAX) {
            float* ad = &g[gg * D + col];
            if (cur >= 0.f) atomicMax((int*)ad, __float_as_int(cur));
            else            atomicMin((unsigned int*)ad, __float_as_uint(cur));
        }
    }
}

// ---------------- head ---------------------------------------------------------

__global__ void mlp_head(const float* __restrict__ g,
                         const float* __restrict__ W1, const float* __restrict__ b1,
                         const float* __restrict__ W2, const float* __restrict__ b2,
                         float* __restrict__ out) {
    int gi = threadIdx.x;
    if (gi >= N_GRAPHS) return;
    float h[5];
#pragma unroll
    for (int j = 0; j < 5; ++j) {
        float acc = b1[j];
        for (int k = 0; k < D; ++k) acc += g[gi * D + k] * W1[j * D + k];
        h[j] = fmaxf(acc, 0.f);
    }
    float o = b2[0];
#pragma unroll
    for (int j = 0; j < 5; ++j) o += h[j] * W2[j];
    out[gi] = o;
}

extern "C" void kernel_launch(void* const* d_in, const int* in_sizes, int n_in,
                              void* d_out, int out_size, void* d_ws, size_t ws_size,
                              hipStream_t stream) {
    const float* x     = (const float*)d_in[0];
    const int*   ei    = (const int*)d_in[1];
    const int*   batch = (const int*)d_in[2];
    const float* Wrel[3]  = {(const float*)d_in[3], (const float*)d_in[6], (const float*)d_in[9]};
    const float* brel[3]  = {(const float*)d_in[4], (const float*)d_in[7], (const float*)d_in[10]};
    const float* Wroot[3] = {(const float*)d_in[5], (const float*)d_in[8], (const float*)d_in[11]};
    const float* W1 = (const float*)d_in[12];
    const float* b1 = (const float*)d_in[13];
    const float* W2 = (const float*)d_in[14];
    const float* b2 = (const float*)d_in[15];
    float* out = (float*)d_out;

    char* ws = (char*)d_ws;
    const size_t nodeB16 = (size_t)N_NODES * D * sizeof(unsigned short);   // 12.8 MB
    unsigned short* xb   = (unsigned short*)(ws);
    unsigned short* aggb = (unsigned short*)(ws + nodeB16);
    unsigned short* hb1  = (unsigned short*)(ws + 2 * nodeB16);
    unsigned short* hb2  = (unsigned short*)(ws + 3 * nodeB16);
    char* p = ws + 4 * nodeB16;
    unsigned short* Bb0 = (unsigned short*)p;   p += 128 * 256 * sizeof(unsigned short);
    unsigned short* Bb1 = (unsigned short*)p;   p += 128 * 256 * sizeof(unsigned short);
    unsigned short* Bb2 = (unsigned short*)p;   p += 128 * 256 * sizeof(unsigned short);
    float* g        = (float*)p;                p += N_GRAPHS * D * sizeof(float);
    int*   deg      = (int*)p;                  p += N_NODES * sizeof(int);
    int*   row_start= (int*)p;                  p += (N_NODES + 1) * sizeof(int);
    int*   cursor   = (int*)p;                  p += N_NODES * sizeof(int);
    int*   csr_src  = (int*)p;                  p += N_EDGES * sizeof(int);
    int*   blockSums= (int*)p;                  p += SCAN_NBLK * sizeof(int);

    // fused prep + bf16 conversions (runs first; zeroes deg for count_deg)
    const int n4 = N_NODES * D / 4;                       // 1.6M
    const int cast_total = n4 + 3 * 128 * 256;
    cast_prep<<<(cast_total + 255) / 256, 256, 0, stream>>>(
        (const float4*)x, (ushort4*)xb, n4,
        Wrel[0], Wroot[0], Wrel[1], Wroot[1], Wrel[2], Wroot[2],
        Bb0, Bb1, Bb2, deg, g);

    // CSR build (once per call)
    count_deg<<<(N_EDGES + 255) / 256, 256, 0, stream>>>(ei, deg);
    block_sum<<<SCAN_NBLK, SCAN_T, 0, stream>>>(deg, blockSums);
    scan_write<<<SCAN_NBLK, SCAN_T, 0, stream>>>(deg, blockSums, row_start, cursor);
    fill_csr<<<(N_EDGES + 255) / 256, 256, 0, stream>>>(ei, cursor, csr_src);

    const int ggrid = (N_NODES + 7) / 8;                  // 6250
    const int mgrid = (N_NODES + 63) / 64;                // 782

    csr_gather_bf16<<<ggrid, 256, 0, stream>>>(xb, row_start, csr_src, aggb);
    gemm_mfma<<<mgrid, 256, 0, stream>>>(aggb, xb, Bb0, brel[0], hb1, 1);

    csr_gather_bf16<<<ggrid, 256, 0, stream>>>(hb1, row_start, csr_src, aggb);
    gemm_mfma<<<mgrid, 256, 0, stream>>>(aggb, hb1, Bb1, brel[1], hb2, 1);

    csr_gather_bf16<<<ggrid, 256, 0, stream>>>(hb2, row_start, csr_src, aggb);
    gemm_pool<<<mgrid, 256, 0, stream>>>(aggb, hb2, Bb2, brel[2], batch, g);

    mlp_head<<<1, 64, 0, stream>>>(g, W1, b1, W2, b2, out);
}